// Round 2
// baseline (626.964 us; speedup 1.0000x reference)
//
#include <hip/hip_runtime.h>

#define STRIDE 264     // LDS row stride in floats (>= 256 valid + 8 pad for float4 overreads)
#define S_TILE 244     // output positions per block; S_TILE+12 = 256 = widest intermediate
#define W_IN   258     // S_TILE + 14 (halo 7 each side)
#define SEQ    8192

__device__ __forceinline__ int uni(int v) { return __builtin_amdgcn_readfirstlane(v); }

// One conv(k)+bias+relu+BN layer: in/out are LDS [C][STRIDE].
// Wave owns 8 consecutive output channels (cobase wave-uniform -> weight loads scalar),
// lane owns 4 consecutive positions p0..p0+3.
// DOFF: global position of output local index 0 is s0 + DOFF. Positions outside
// [0,SEQ) are forced to 0 to match the reference's per-layer zero padding.
template<int CIN, int K, int WOUT, int DOFF>
__device__ __forceinline__ void conv_bn_relu(
    const float* __restrict__ w, const float* __restrict__ bias,
    const float* __restrict__ g, const float* __restrict__ bb,
    const float* __restrict__ rm, const float* __restrict__ rv,
    const float* in, float* out, int cobase, int p0, int s0)
{
    constexpr int WINN = ((K + 3 + 3) / 4) * 4;   // window floats, rounded to float4
    float acc[8][4];
#pragma unroll
    for (int j = 0; j < 8; ++j) {
        float bj = bias[cobase + j];
#pragma unroll
        for (int i = 0; i < 4; ++i) acc[j][i] = bj;
    }
    for (int ci = 0; ci < CIN; ++ci) {
        float win[WINN];
        const float* row = in + ci * STRIDE + p0;   // p0 = 4*lane -> 16B aligned
#pragma unroll
        for (int v = 0; v < WINN / 4; ++v) {
            float4 t = *(const float4*)(row + 4 * v);
            win[4*v+0] = t.x; win[4*v+1] = t.y; win[4*v+2] = t.z; win[4*v+3] = t.w;
        }
#pragma unroll
        for (int j = 0; j < 8; ++j) {
            const float* wp = w + ((cobase + j) * CIN + ci) * K;  // uniform address
#pragma unroll
            for (int k = 0; k < K; ++k) {
                float wv = wp[k];
#pragma unroll
                for (int i = 0; i < 4; ++i)
                    acc[j][i] = fmaf(win[k + i], wv, acc[j][i]);
            }
        }
    }
    // BN (inference) epilogue: relu -> *scale + shift; zero outside sequence.
#pragma unroll
    for (int j = 0; j < 8; ++j) {
        int co = cobase + j;
        float scale = g[co] / sqrtf(rv[co] + 1e-5f);
        float shift = bb[co] - rm[co] * scale;
        float* orow = out + co * STRIDE;
#pragma unroll
        for (int i = 0; i < 4; ++i) {
            int p = p0 + i;
            float v = fmaxf(acc[j][i], 0.0f) * scale + shift;
            // Reference zero-pads each conv input at sequence edges; an
            // out-of-sequence intermediate must be 0, not its computed value.
            if ((unsigned)(s0 + DOFF + p) >= SEQ) v = 0.0f;
            if (p < WOUT) orow[p] = v;   // positions >= WOUT are halo garbage, dropped
        }
    }
}

extern "C" __global__ void __launch_bounds__(256, 2)
dnashape_fused(const float* __restrict__ x,
    const float* __restrict__ w0, const float* __restrict__ b0, const float* __restrict__ g0,
    const float* __restrict__ bb0, const float* __restrict__ rm0, const float* __restrict__ rv0,
    const float* __restrict__ w1, const float* __restrict__ b1, const float* __restrict__ g1,
    const float* __restrict__ bb1, const float* __restrict__ rm1, const float* __restrict__ rv1,
    const float* __restrict__ w2, const float* __restrict__ b2, const float* __restrict__ g2,
    const float* __restrict__ bb2, const float* __restrict__ rm2, const float* __restrict__ rv2,
    const float* __restrict__ w3, const float* __restrict__ b3, const float* __restrict__ g3,
    const float* __restrict__ bb3, const float* __restrict__ rm3, const float* __restrict__ rv3,
    const float* __restrict__ fw1, const float* __restrict__ fb1,
    const float* __restrict__ fw2, const float* __restrict__ fb2,
    float* __restrict__ out)
{
    __shared__ float bufI[4  * STRIDE];
    __shared__ float bufA[32 * STRIDE];
    __shared__ float bufB[32 * STRIDE];

    const int tile = blockIdx.x;
    const int b    = blockIdx.y;
    const int s0   = tile * S_TILE;
    const int base = s0 - 7;            // input buffer origin (halo 7)
    const int tid  = threadIdx.x;

    // Stage 0: global -> LDS input tile, zero-padded at sequence edges
#pragma unroll
    for (int c = 0; c < 4; ++c) {
        for (int i = tid; i < W_IN; i += 256) {
            int sg = base + i;
            float v = (sg >= 0 && sg < SEQ) ? x[(b * 4 + c) * SEQ + sg] : 0.0f;
            bufI[c * STRIDE + i] = v;
        }
    }
    __syncthreads();

    const int wave   = uni(tid >> 6);   // force wave-uniform for scalar weight loads
    const int lane   = tid & 63;
    const int cobase = wave * 8;
    const int p0     = lane * 4;

    // Buffer origins: in = s0-7, L0out = s0-6, L1out = s0-5, L2out = s0-3, L3out = s0.
    conv_bn_relu<4,  3, 256, -6>(w0, b0, g0, bb0, rm0, rv0, bufI, bufA, cobase, p0, s0);
    __syncthreads();
    conv_bn_relu<32, 3, 254, -5>(w1, b1, g1, bb1, rm1, rv1, bufA, bufB, cobase, p0, s0);
    __syncthreads();
    conv_bn_relu<32, 5, 250, -3>(w2, b2, g2, bb2, rm2, rv2, bufB, bufA, cobase, p0, s0);
    __syncthreads();
    conv_bn_relu<32, 7, S_TILE, 0>(w3, b3, g3, bb3, rm3, rv3, bufA, bufB, cobase, p0, s0);
    __syncthreads();

    // Stage 5: per-position MLP 32 -> 16 (relu) -> 1
    if (tid < S_TILE) {
        int s = s0 + tid;
        if (s < SEQ) {
            float xv[32];
#pragma unroll
            for (int c = 0; c < 32; ++c) xv[c] = bufB[c * STRIDE + tid];
            float o = fb2[0];
#pragma unroll
            for (int h = 0; h < 16; ++h) {
                float a = fb1[h];
#pragma unroll
                for (int c = 0; c < 32; ++c) a = fmaf(xv[c], fw1[h * 32 + c], a);
                o = fmaf(fmaxf(a, 0.0f), fw2[h], o);
            }
            out[b * SEQ + s] = o;
        }
    }
}

extern "C" void kernel_launch(void* const* d_in, const int* in_sizes, int n_in,
                              void* d_out, int out_size, void* d_ws, size_t ws_size,
                              hipStream_t stream) {
    const float* p[29];
    for (int i = 0; i < 29; ++i) p[i] = (const float*)d_in[i];
    dim3 grid((SEQ + S_TILE - 1) / S_TILE, 128);   // 34 x 128
    dnashape_fused<<<grid, 256, 0, stream>>>(p[0],
        p[1],  p[2],  p[3],  p[4],  p[5],  p[6],
        p[7],  p[8],  p[9],  p[10], p[11], p[12],
        p[13], p[14], p[15], p[16], p[17], p[18],
        p[19], p[20], p[21], p[22], p[23], p[24],
        p[25], p[26], p[27], p[28],
        (float*)d_out);
}

// Round 3
// 555.674 us; speedup vs baseline: 1.1283x; 1.1283x over previous
//
#include <hip/hip_runtime.h>

#define STRIDE 264     // LDS row stride in floats (256 valid + 8 pad for float4 overreads)
#define S_TILE 244     // output positions per block; S_TILE+12 = 256 = widest intermediate
#define W_IN   258     // S_TILE + 14 (halo 7 each side)
#define SEQ    8192
#define NTHR   512     // 8 waves; wave owns 4 channels, lane owns 4 positions

__device__ __forceinline__ int uni(int v) { return __builtin_amdgcn_readfirstlane(v); }

// One conv(k)+bias+relu+BN layer: in/out are LDS [C][STRIDE].
// Wave owns 4 consecutive output channels (cobase wave-uniform -> scalar weight loads),
// lane owns 4 consecutive positions p0..p0+3 (p0 = 4*lane, 16B aligned).
// DOFF: global position of output local index 0 is s0 + DOFF; outside [0,SEQ) -> 0
// to match the reference's per-layer zero padding.
// Stores are unconditional ds_write_b128: positions beyond the layer's valid width
// hold garbage but stay inside the padded row and are never consumed downstream
// (valid widths shrink by K-1 per layer; window overreads land in unused win slots).
template<int CIN, int K, int DOFF>
__device__ __forceinline__ void conv_bn_relu(
    const float* __restrict__ w, const float* __restrict__ bias,
    const float* __restrict__ g, const float* __restrict__ bb,
    const float* __restrict__ rm, const float* __restrict__ rv,
    const float* in, float* out, int cobase, int p0, int s0)
{
    constexpr int WINN = ((K + 3 + 3) / 4) * 4;   // window floats, rounded to float4
    float acc[4][4];
#pragma unroll
    for (int j = 0; j < 4; ++j) {
        float bj = bias[cobase + j];
#pragma unroll
        for (int i = 0; i < 4; ++i) acc[j][i] = bj;
    }
    for (int ci = 0; ci < CIN; ++ci) {
        float win[WINN];
        const float* row = in + ci * STRIDE + p0;
#pragma unroll
        for (int v = 0; v < WINN / 4; ++v) {
            float4 t = *(const float4*)(row + 4 * v);
            win[4*v+0] = t.x; win[4*v+1] = t.y; win[4*v+2] = t.z; win[4*v+3] = t.w;
        }
#pragma unroll
        for (int j = 0; j < 4; ++j) {
            const float* wp = w + ((cobase + j) * CIN + ci) * K;  // uniform address
#pragma unroll
            for (int k = 0; k < K; ++k) {
                float wv = wp[k];
#pragma unroll
                for (int i = 0; i < 4; ++i)
                    acc[j][i] = fmaf(win[k + i], wv, acc[j][i]);
            }
        }
    }
    // BN (inference) epilogue: relu -> *scale + shift; zero outside sequence; b128 store.
#pragma unroll
    for (int j = 0; j < 4; ++j) {
        int co = cobase + j;
        float scale = g[co] / sqrtf(rv[co] + 1e-5f);
        float shift = bb[co] - rm[co] * scale;
        float4 vv;
#pragma unroll
        for (int i = 0; i < 4; ++i) {
            float v = fmaxf(acc[j][i], 0.0f) * scale + shift;
            if ((unsigned)(s0 + DOFF + p0 + i) >= SEQ) v = 0.0f;
            (&vv.x)[i] = v;
        }
        *(float4*)(out + co * STRIDE + p0) = vv;   // 16B/lane, conflict-free
    }
}

extern "C" __global__ void __launch_bounds__(NTHR, 4)
dnashape_fused(const float* __restrict__ x,
    const float* __restrict__ w0, const float* __restrict__ b0, const float* __restrict__ g0,
    const float* __restrict__ bb0, const float* __restrict__ rm0, const float* __restrict__ rv0,
    const float* __restrict__ w1, const float* __restrict__ b1, const float* __restrict__ g1,
    const float* __restrict__ bb1, const float* __restrict__ rm1, const float* __restrict__ rv1,
    const float* __restrict__ w2, const float* __restrict__ b2, const float* __restrict__ g2,
    const float* __restrict__ bb2, const float* __restrict__ rm2, const float* __restrict__ rv2,
    const float* __restrict__ w3, const float* __restrict__ b3, const float* __restrict__ g3,
    const float* __restrict__ bb3, const float* __restrict__ rm3, const float* __restrict__ rv3,
    const float* __restrict__ fw1, const float* __restrict__ fb1,
    const float* __restrict__ fw2, const float* __restrict__ fb2,
    float* __restrict__ out)
{
    // bufB doubles as the input buffer (rows 0..3) for layer 0; layer 1 overwrites
    // it only after layer 0 consumed it. Total LDS = 64 rows = 67.6 KB -> 2 blocks/CU.
    __shared__ float bufA[32 * STRIDE];
    __shared__ float bufB[32 * STRIDE];

    const int tile = blockIdx.x;
    const int b    = blockIdx.y;
    const int s0   = tile * S_TILE;
    const int base = s0 - 7;            // input buffer origin (halo 7)
    const int tid  = threadIdx.x;

    // Stage 0: global -> LDS input tile (into bufB rows 0..3), zero-padded at edges
#pragma unroll
    for (int c = 0; c < 4; ++c) {
        for (int i = tid; i < W_IN; i += NTHR) {
            int sg = base + i;
            float v = (sg >= 0 && sg < SEQ) ? x[(b * 4 + c) * SEQ + sg] : 0.0f;
            bufB[c * STRIDE + i] = v;
        }
    }
    __syncthreads();

    const int wave   = uni(tid >> 6);   // wave-uniform for scalar weight loads
    const int lane   = tid & 63;
    const int cobase = wave * 4;        // 8 waves x 4 channels = 32
    const int p0     = lane * 4;

    // Buffer origins: in = s0-7, L0out = s0-6, L1out = s0-5, L2out = s0-3, L3out = s0.
    conv_bn_relu<4,  3, -6>(w0, b0, g0, bb0, rm0, rv0, bufB, bufA, cobase, p0, s0);
    __syncthreads();
    conv_bn_relu<32, 3, -5>(w1, b1, g1, bb1, rm1, rv1, bufA, bufB, cobase, p0, s0);
    __syncthreads();
    conv_bn_relu<32, 5, -3>(w2, b2, g2, bb2, rm2, rv2, bufB, bufA, cobase, p0, s0);
    __syncthreads();
    conv_bn_relu<32, 7,  0>(w3, b3, g3, bb3, rm3, rv3, bufA, bufB, cobase, p0, s0);
    __syncthreads();

    // Stage 5: per-position MLP 32 -> 16 (relu) -> 1
    if (tid < S_TILE) {
        int s = s0 + tid;
        if (s < SEQ) {
            float xv[32];
#pragma unroll
            for (int c = 0; c < 32; ++c) xv[c] = bufB[c * STRIDE + tid];
            float o = fb2[0];
#pragma unroll
            for (int h = 0; h < 16; ++h) {
                float a = fb1[h];
#pragma unroll
                for (int c = 0; c < 32; ++c) a = fmaf(xv[c], fw1[h * 32 + c], a);
                o = fmaf(fmaxf(a, 0.0f), fw2[h], o);
            }
            out[b * SEQ + s] = o;
        }
    }
}

extern "C" void kernel_launch(void* const* d_in, const int* in_sizes, int n_in,
                              void* d_out, int out_size, void* d_ws, size_t ws_size,
                              hipStream_t stream) {
    const float* p[29];
    for (int i = 0; i < 29; ++i) p[i] = (const float*)d_in[i];
    dim3 grid((SEQ + S_TILE - 1) / S_TILE, 128);   // 34 x 128
    dnashape_fused<<<grid, NTHR, 0, stream>>>(p[0],
        p[1],  p[2],  p[3],  p[4],  p[5],  p[6],
        p[7],  p[8],  p[9],  p[10], p[11], p[12],
        p[13], p[14], p[15], p[16], p[17], p[18],
        p[19], p[20], p[21], p[22], p[23], p[24],
        p[25], p[26], p[27], p[28],
        (float*)d_out);
}